// Round 8
// baseline (1098.813 us; speedup 1.0000x reference)
//
#include <hip/hip_runtime.h>

#define T_SEQ 200
#define NB    32
#define NE    300
#define NH    1000
#define NK    9
#define NJ    4096          // xg rows per t
#define EPD   320           // padded embed K
#define WSCALE 256.0f
#define HSCALE 16.0f
#define LSCALE 512.0f
#define GSCALE (1.0f / (256.0f * 16.0f))
#define TSCALE (1.0f / (16.0f * 512.0f))

typedef __attribute__((ext_vector_type(4))) float f32x4;
typedef __attribute__((ext_vector_type(8))) short s16x8;
typedef __attribute__((ext_vector_type(4))) short s16x4;
typedef unsigned long long u64;

__device__ __forceinline__ unsigned short f2bf(float f) {
    union { float f; unsigned u; } v; v.f = f;
    unsigned r = v.u + 0x7FFFu + ((v.u >> 16) & 1u);   // RNE
    return (unsigned short)(r >> 16);
}
__device__ __forceinline__ float bf2f(unsigned short h) {
    union { unsigned u; float f; } v; v.u = ((unsigned)h) << 16;
    return v.f;
}
__device__ __forceinline__ float ftanh(float x) {
    float e = __expf(fminf(2.f * x, 80.f));
    return (e - 1.f) / (e + 1.f);
}
__device__ __forceinline__ float fsig(float x) {
    return 1.f / (1.f + __expf(-x));
}
// non-temporal dword load: no L1 allocate -> served by (XCD) L2
__device__ __forceinline__ unsigned nt_poll(const unsigned* p) {
    unsigned r;
    asm volatile("global_load_dword %0, %1, off nt\n\t"
                 "s_waitcnt vmcnt(0)"
                 : "=v"(r) : "v"(p) : "memory");
    return r;
}
// plain store, compiler-opaque (workgroup-scope relaxed -> global_store_dword)
__device__ __forceinline__ void plain_pub(unsigned* p, unsigned v) {
    __hip_atomic_store(p, v, __ATOMIC_RELAXED, __HIP_MEMORY_SCOPE_WORKGROUP);
}

// ---------------------------------------------------------------------------
// ctrl map (dwords):
// [0..63]    slowf group0 (agent/MALL, 64 per-wave flags)
// [64..127]  slowf group1
// [128..191] fastf group0 (plain/L2, 64 per-wave flags)
// [192..255] fastf group1
// [256..455] done[t]
// [480..495] XCD tickets | [496] arrivals | [497] winners (w0|w1<<8, init -1)
// [498] prod ticket | [499] mode verdict (0=undecided, 1=nt/L2, 2=agent/MALL)
// [512..711] em page flags (tagem_crf)
// ---------------------------------------------------------------------------
// fused prep: blocks [0..199] = embedding gather+cvt (+ctrl init at blk 0),
// blocks [200..263] = W_ih cvt + bias + lin_w fp8 quant.
// ---------------------------------------------------------------------------
__global__ __launch_bounds__(256) void prep_all(
    const int* __restrict__ x, const float* __restrict__ embed_w,
    const float* __restrict__ W_ih, const float* __restrict__ b_ih,
    const float* __restrict__ b_hh, const float* __restrict__ lin_w,
    unsigned short* __restrict__ emb_bf, unsigned short* __restrict__ wih_bf,
    float* __restrict__ biasg, unsigned char* __restrict__ linw_q,
    unsigned* __restrict__ ctrl)
{
    const int blk = blockIdx.x, tid = threadIdx.x;
    if (blk < T_SEQ) {
        const int t = blk;
        if (blk == 0) {
            for (int i = tid; i < 2048; i += 256)
                ctrl[i] = (i == 497) ? 0xffffffffu : 0u;
        }
        for (int idx = tid; idx < NB * EPD; idx += 256) {
            int b = idx / EPD, e = idx - b * EPD;
            float v = (e < NE) ? embed_w[(size_t)x[t * NB + b] * NE + e] : 0.f;
            emb_bf[((size_t)t * NB + b) * EPD + e] = f2bf(v);
        }
        return;
    }
    const int b2 = blk - T_SEQ;      // 0..63
    for (int idx = tid; idx < 64 * EPD; idx += 256) {
        int jr = idx / EPD, e = idx - jr * EPD;
        int jp = b2 * 64 + jr;
        int wgu = jp >> 7, rr = jp & 127, g = rr >> 5, uu = rr & 31;
        int m = wgu * 32 + uu;
        float v = (m < NH && e < NE) ? W_ih[(size_t)(g * NH + m) * NE + e] : 0.f;
        wih_bf[(size_t)jp * EPD + e] = f2bf(v);
    }
    if (tid < 64) {
        int jp = b2 * 64 + tid;
        int wgu = jp >> 7, rr = jp & 127, g = rr >> 5, uu = rr & 31;
        int m = wgu * 32 + uu;
        biasg[jp] = (m < NH) ? (b_ih[g * NH + m] + b_hh[g * NH + m]) : 0.f;
    }
    if (b2 < 16) {
        int n = b2, k = tid * 4;
        float v0 = (n < NK && k + 0 < NH) ? lin_w[(size_t)n * NH + k + 0] * LSCALE : 0.f;
        float v1 = (n < NK && k + 1 < NH) ? lin_w[(size_t)n * NH + k + 1] * LSCALE : 0.f;
        float v2 = (n < NK && k + 2 < NH) ? lin_w[(size_t)n * NH + k + 2] * LSCALE : 0.f;
        float v3 = (n < NK && k + 3 < NH) ? lin_w[(size_t)n * NH + k + 3] * LSCALE : 0.f;
        int p01 = __builtin_amdgcn_cvt_pk_fp8_f32(v0, v1, 0, false);
        int p23 = __builtin_amdgcn_cvt_pk_fp8_f32(v2, v3, 0, false);
        ((unsigned*)linw_q)[n * 256 + tid] =
            ((unsigned)p01 & 0xffffu) | ((unsigned)p23 << 16);
    }
}

// ---------------------------------------------------------------------------
__device__ __forceinline__ int gate_xg(unsigned* done, int ready, int tn, int lane) {
    while (ready <= tn) {
        unsigned v = 64u;
        if (lane < 8 && ready + lane < T_SEQ)
            v = __hip_atomic_load(&done[ready + lane], __ATOMIC_RELAXED,
                                  __HIP_MEMORY_SCOPE_AGENT);
        unsigned m = (unsigned)__ballot((int)(v >= 64u)) & 255u;
        if (m & 1u) {
            unsigned run = (m == 255u) ? 8u : (unsigned)__builtin_ctz(~m);
            ready += (int)run;
        } else {
            __builtin_amdgcn_s_sleep(1);
        }
    }
    return ready;
}

// ---------------------------------------------------------------------------
// mega kernel (R3/R4 frozen structure + split-half skew/compute overlap).
// grid 256, 1 WG/CU. TWO winner XCDs each host an independent 32-WG consumer
// group handling 16 batch lanes. Per consumer WG: 2 compute waves (p=0,1),
// each owning its OWN readiness flag (64 flags/group) -> NO barriers in the
// recurrence loop; waves 2,3 exit before the loop.
// NEW (this round): each step's consume is split by K-halves. Phase 1 waits
// only for chunks 0..15 (flags 0..31), RECORDING half-2 status from the same
// poll; loads+MFMAs half 1 (overlaps half-2 stragglers with compute); a
// conditional phase-2 poll runs ONLY if half 2 wasn't ready at phase-1 exit
// (zero extra L2 round-trip when skew is absent). Summation order kc=0..31
// preserved -> bit-identical results. xg prefetch stays after all a-loads,
// before the last MFMA block (R4-proven placement).
// ---------------------------------------------------------------------------
__global__ __launch_bounds__(256, 1) void lstm_kernel(
    const float* __restrict__ W_hh,
    const unsigned short* __restrict__ emb_bf,
    const unsigned short* __restrict__ wih_bf,
    const float* __restrict__ biasg,
    unsigned short* __restrict__ xg,
    unsigned char* __restrict__ h_q,
    unsigned* __restrict__ ctrl)
{
    __shared__ __align__(16) unsigned char s_w[128 * 1024];   // 131,072 B
    __shared__ int s_chunk, s_grp, s_pid, s_mode;

    const int tid = threadIdx.x;

    // ---- election (startup only, MALL atomics) ----
    if (tid == 0) {
        unsigned xcc;
        asm volatile("s_getreg_b32 %0, hwreg(HW_REG_XCC_ID)" : "=s"(xcc));
        xcc &= 15u;
        unsigned myidx = __hip_atomic_fetch_add(&ctrl[480 + xcc], 1u,
                             __ATOMIC_RELAXED, __HIP_MEMORY_SCOPE_AGENT);
        __threadfence();
        unsigned tot = __hip_atomic_fetch_add(&ctrl[496], 1u,
                             __ATOMIC_RELAXED, __HIP_MEMORY_SCOPE_AGENT);
        if (tot == 255u) {
            __threadfence();
            unsigned w0 = 0xffu, w1 = 0xffu;
            for (unsigned xx = 0; xx < 16; ++xx) {
                unsigned cx = __hip_atomic_load(&ctrl[480 + xx], __ATOMIC_RELAXED,
                                                __HIP_MEMORY_SCOPE_AGENT);
                if (cx >= 32u) {
                    if (w0 == 0xffu) w0 = xx;
                    else { w1 = xx; break; }
                }
            }
            __hip_atomic_store(&ctrl[497], w0 | (w1 << 8), __ATOMIC_RELAXED,
                               __HIP_MEMORY_SCOPE_AGENT);
        }
        unsigned win;
        do {
            win = __hip_atomic_load(&ctrl[497], __ATOMIC_RELAXED,
                                    __HIP_MEMORY_SCOPE_AGENT);
        } while (win == 0xffffffffu);
        unsigned w0 = win & 0xffu, w1 = (win >> 8) & 0xffu;
        int grp = -1;
        if (xcc == w0 && myidx < 32u) grp = 0;
        else if (xcc == w1 && myidx < 32u) grp = 1;
        s_grp = grp;
        s_chunk = (grp >= 0) ? (int)myidx : -1;
        s_pid = (grp >= 0) ? -1
                     : (int)__hip_atomic_fetch_add(&ctrl[498], 1u,
                           __ATOMIC_RELAXED, __HIP_MEMORY_SCOPE_AGENT);
    }
    __syncthreads();
    const int chunk = s_chunk;
    const int w = tid >> 6, lane = tid & 63;
    const int col = lane & 15, quad = lane >> 4;
    unsigned* done = ctrl + 256;

    if (chunk < 0) {
        // =================== PRODUCER: xg projection tiles ===================
        const int pid = s_pid;
        for (int g = pid; g < T_SEQ * 64; g += 192) {
            const int t = g >> 6, jt = g & 63;
            const unsigned short* eb = emb_bf + (size_t)t * NB * EPD;
            const unsigned short* wb = wih_bf + (size_t)(jt * 64 + w * 16 + col) * EPD;
            const unsigned short* ea0 = eb + (size_t)col * EPD;
            const unsigned short* ea1 = eb + (size_t)(16 + col) * EPD;

            f32x4 acc0 = {0.f, 0.f, 0.f, 0.f};
            f32x4 acc1 = {0.f, 0.f, 0.f, 0.f};
#pragma unroll
            for (int kc = 0; kc < EPD / 32; ++kc) {
                int ko = kc * 32 + quad * 8;
                s16x8 a0 = *(const s16x8*)&ea0[ko];
                s16x8 a1 = *(const s16x8*)&ea1[ko];
                s16x8 bb = *(const s16x8*)&wb[ko];
                acc0 = __builtin_amdgcn_mfma_f32_16x16x32_bf16(a0, bb, acc0, 0, 0, 0);
                acc1 = __builtin_amdgcn_mfma_f32_16x16x32_bf16(a1, bb, acc1, 0, 0, 0);
            }
            const int jp = jt * 64 + w * 16 + col;
            const float bi = biasg[jp];
            size_t base = ((size_t)t * NJ + jp) * NB;
            union { s16x4 v; u64 q; } p0, p1;
#pragma unroll
            for (int r = 0; r < 4; ++r) {
                p0.v[r] = (short)f2bf(acc0[r] + bi);
                p1.v[r] = (short)f2bf(acc1[r] + bi);
            }
            __hip_atomic_store((u64*)&xg[base + quad * 4], p0.q,
                               __ATOMIC_RELAXED, __HIP_MEMORY_SCOPE_AGENT);
            __hip_atomic_store((u64*)&xg[base + 16 + quad * 4], p1.q,
                               __ATOMIC_RELAXED, __HIP_MEMORY_SCOPE_AGENT);
            __syncthreads();   // stores vmcnt-drained (MALL-ack'd)
            if (tid == 0)
                __hip_atomic_fetch_add(&done[t], 1u, __ATOMIC_RELAXED,
                                       __HIP_MEMORY_SCOPE_AGENT);
        }
        return;
    }

    // ===================== CONSUMER: LSTM recurrence =====================
    const int grp = s_grp;
    const size_t GOFF = (size_t)grp * 16384;     // group's half of each 32 KB page
    unsigned* slowf = ctrl + grp * 64;           // agent fallback flags (64)
    unsigned* fastf = ctrl + 128 + grp * 64;     // plain/L2 flags (64)
    unsigned* s_w32 = (unsigned*)s_w;

    // ---- stage W_hh -> LDS fp8 x256, XOR-swizzled on 8-B blocks ----
    for (int idx = tid; idx < 128 * 256; idx += 256) {
        int r = idx >> 8, dw = idx & 255;
        int g = r >> 5, uu = r & 31, m = chunk * 32 + uu;
        float4 w4 = make_float4(0.f, 0.f, 0.f, 0.f);
        if (m < NH && dw < 250)
            w4 = *(const float4*)&W_hh[(size_t)(g * NH + m) * NH + dw * 4];
        int p0 = __builtin_amdgcn_cvt_pk_fp8_f32(w4.x * WSCALE, w4.y * WSCALE, 0, false);
        int p1 = __builtin_amdgcn_cvt_pk_fp8_f32(w4.z * WSCALE, w4.w * WSCALE, 0, false);
        unsigned v = ((unsigned)p0 & 0xffffu) | ((unsigned)p1 << 16);
        int kb = dw >> 1;
        int kbs = kb ^ (r & 15);
        s_w32[r * 256 + (kbs << 1) + (dw & 1)] = v;
    }
    // ---- zero own 512-B chunk of page 0 (plain store -> local L2) ----
    if (tid < 128)
        *(unsigned*)(h_q + GOFF + (size_t)chunk * 512 + tid * 4) = 0u;
    __syncthreads();   // W tile in LDS; page-0 zeros vmcnt-drained (all waves)
    if (tid == 0) {
        plain_pub(&fastf[chunk * 2 + 0], 1u);
        plain_pub(&fastf[chunk * 2 + 1], 1u);
        __hip_atomic_store(&slowf[chunk * 2 + 0], 1u, __ATOMIC_RELAXED,
                           __HIP_MEMORY_SCOPE_AGENT);
        __hip_atomic_store(&slowf[chunk * 2 + 1], 1u, __ATOMIC_RELAXED,
                           __HIP_MEMORY_SCOPE_AGENT);
    }
    // ---- nt-visibility self-test; group0/chunk0 decides, ctrl[499] bcast ----
    if (grp == 0 && chunk == 0 && w == 0) {
        int md = 2;
        for (int it = 0; it < 8192; ++it) {
            unsigned v = nt_poll(&fastf[lane]);
            if (__all((int)(v >= 1u))) { md = 1; break; }
        }
        if (lane == 0) {
            __hip_atomic_store(&ctrl[499], (unsigned)md, __ATOMIC_RELAXED,
                               __HIP_MEMORY_SCOPE_AGENT);
            s_mode = md;
        }
    } else if (tid == 0) {
        unsigned m;
        do {
            m = __hip_atomic_load(&ctrl[499], __ATOMIC_RELAXED,
                                  __HIP_MEMORY_SCOPE_AGENT);
        } while (m == 0u);
        s_mode = (int)m;
    }
    __syncthreads();
    const int mode = s_mode;

    // ---- waves 2,3 exit: no barriers remain in the recurrence loop ----
    if (w >= 2) return;
    const int p = w;                 // p-half of the chunk's 32 units
    const int fid = chunk * 2 + w;   // this wave's own flag

    // ---- gated xg load t=0; pre-gate page 1 for issue at top of t=0 ----
    int ready = gate_xg(done, 0, 1, lane);
    s16x4 xcur[4], xnxt[4];
#pragma unroll
    for (int g = 0; g < 4; ++g)
        xcur[g] = *(const s16x4*)&xg[((size_t)0 * NJ + chunk * 128 + (2 * g + p) * 16 + col) * NB
                                     + grp * 16 + quad * 4];

    float c[4] = {0.f, 0.f, 0.f, 0.f};
    const int rw = quad * 4;
    const int boff = col * 32 + quad * 8;

    for (int t = 0; t < T_SEQ; ++t) {
        // ---- phase-1 poll: half-1 flags (chunks 0..15 = flags 0..31) +
        //      producer gate for page t+2; half-2 status recorded ----
        const unsigned need = (unsigned)(t + 1);
        const int gt = t + 2;
        bool gate_pending = (gt < T_SEQ) && (ready <= gt);
        bool half2_ready = false;
        if (mode == 1) {
            for (;;) {
                unsigned v = nt_poll(&fastf[lane]);
                u64 bal = __ballot((int)(v >= need));
                if (gate_pending) {
                    unsigned d = 64u;
                    if (lane < 8 && ready + lane < T_SEQ)
                        d = __hip_atomic_load(&done[ready + lane], __ATOMIC_RELAXED,
                                              __HIP_MEMORY_SCOPE_AGENT);
                    unsigned m = (unsigned)__ballot((int)(d >= 64u)) & 255u;
                    if (m & 1u)
                        ready += (m == 255u) ? 8 : (int)__builtin_ctz(~m);
                    gate_pending = (ready <= gt);
                }
                if ((unsigned)bal == 0xffffffffu && !gate_pending) {
                    half2_ready = ((unsigned)(bal >> 32) == 0xffffffffu);
                    break;
                }
            }
        } else {
            for (;;) {
                unsigned v = __hip_atomic_load(&slowf[lane], __ATOMIC_RELAXED,
                                               __HIP_MEMORY_SCOPE_AGENT);
                u64 bal = __ballot((int)(v >= need));
                if (gate_pending) {
                    unsigned d = 64u;
                    if (lane < 8 && ready + lane < T_SEQ)
                        d = __hip_atomic_load(&done[ready + lane], __ATOMIC_RELAXED,
                                              __HIP_MEMORY_SCOPE_AGENT);
                    unsigned m = (unsigned)__ballot((int)(d >= 64u)) & 255u;
                    if (m & 1u)
                        ready += (m == 255u) ? 8 : (int)__builtin_ctz(~m);
                    gate_pending = (ready <= gt);
                }
                if ((unsigned)bal == 0xffffffffu && !gate_pending) {
                    half2_ready = ((unsigned)(bal >> 32) == 0xffffffffu);
                    break;
                }
            }
        }
        asm volatile("" ::: "memory");

        // ---- half-1: burst load chunks 0..15 (8 KB, local L2) + MFMA ----
        const unsigned char* pb = h_q + (size_t)t * 32768 + GOFF + boff;
        u64 a[32];
#pragma unroll
        for (int kc = 0; kc < 16; ++kc)
            a[kc] = *(const u64*)(pb + (size_t)kc * 512);

        f32x4 acc0 = {0.f, 0.f, 0.f, 0.f};
        f32x4 acc1 = {0.f, 0.f, 0.f, 0.f};
        f32x4 acc2 = {0.f, 0.f, 0.f, 0.f};
        f32x4 acc3 = {0.f, 0.f, 0.f, 0.f};
#pragma unroll
        for (int kc = 0; kc < 16; ++kc) {
            int kb = kc * 4 + quad;
            u64 b0 = *(const u64*)&s_w[((0 * 2 + p) * 16 + col) * 1024 + ((kb ^ col) << 3)];
            u64 b1 = *(const u64*)&s_w[((1 * 2 + p) * 16 + col) * 1024 + ((kb ^ col) << 3)];
            u64 b2 = *(const u64*)&s_w[((2 * 2 + p) * 16 + col) * 1024 + ((kb ^ col) << 3)];
            u64 b3 = *(const u64*)&s_w[((3 * 2 + p) * 16 + col) * 1024 + ((kb ^ col) << 3)];
            acc0 = __builtin_amdgcn_mfma_f32_16x16x32_fp8_fp8((long)a[kc], (long)b0, acc0, 0, 0, 0);
            acc1 = __builtin_amdgcn_mfma_f32_16x16x32_fp8_fp8((long)a[kc], (long)b1, acc1, 0, 0, 0);
            acc2 = __builtin_amdgcn_mfma_f32_16x16x32_fp8_fp8((long)a[kc], (long)b2, acc2, 0, 0, 0);
            acc3 = __builtin_amdgcn_mfma_f32_16x16x32_fp8_fp8((long)a[kc], (long)b3, acc3, 0, 0, 0);
        }

        // ---- phase-2 poll: ONLY if half 2 wasn't ready at phase-1 exit ----
        if (!half2_ready) {
            if (mode == 1) {
                for (;;) {
                    unsigned v = (lane >= 32) ? nt_poll(&fastf[lane]) : need;
                    if (__all((int)(v >= need))) break;
                }
            } else {
                for (;;) {
                    unsigned v = (lane >= 32)
                        ? __hip_atomic_load(&slowf[lane], __ATOMIC_RELAXED,
                                            __HIP_MEMORY_SCOPE_AGENT)
                        : need;
                    if (__all((int)(v >= need))) break;
                }
            }
            asm volatile("" ::: "memory");
        }

        // ---- half-2: burst load chunks 16..31 ----
#pragma unroll
        for (int kc = 16; kc < 32; ++kc)
            a[kc] = *(const u64*)(pb + (size_t)kc * 512);

        // ---- xg prefetch t+1 (after ALL a-loads: a[] waitable without
        //      touching the MALL loads; R4-proven placement) ----
        if (t + 1 < T_SEQ) {
#pragma unroll
            for (int g = 0; g < 4; ++g)
                xnxt[g] = *(const s16x4*)&xg[((size_t)(t + 1) * NJ + chunk * 128 + (2 * g + p) * 16 + col) * NB
                                             + grp * 16 + quad * 4];
        }

#pragma unroll
        for (int kc = 16; kc < 32; ++kc) {
            int kb = kc * 4 + quad;
            u64 b0 = *(const u64*)&s_w[((0 * 2 + p) * 16 + col) * 1024 + ((kb ^ col) << 3)];
            u64 b1 = *(const u64*)&s_w[((1 * 2 + p) * 16 + col) * 1024 + ((kb ^ col) << 3)];
            u64 b2 = *(const u64*)&s_w[((2 * 2 + p) * 16 + col) * 1024 + ((kb ^ col) << 3)];
            u64 b3 = *(const u64*)&s_w[((3 * 2 + p) * 16 + col) * 1024 + ((kb ^ col) << 3)];
            acc0 = __builtin_amdgcn_mfma_f32_16x16x32_fp8_fp8((long)a[kc], (long)b0, acc0, 0, 0, 0);
            acc1 = __builtin_amdgcn_mfma_f32_16x16x32_fp8_fp8((long)a[kc], (long)b1, acc1, 0, 0, 0);
            acc2 = __builtin_amdgcn_mfma_f32_16x16x32_fp8_fp8((long)a[kc], (long)b2, acc2, 0, 0, 0);
            acc3 = __builtin_amdgcn_mfma_f32_16x16x32_fp8_fp8((long)a[kc], (long)b3, acc3, 0, 0, 0);
        }

        // ---- epilogue: 4 cells; direct byte stores (group-local layout) ----
        float hv[4];
#pragma unroll
        for (int r = 0; r < 4; ++r) {
            float gi = acc0[r] * GSCALE + bf2f((unsigned short)xcur[0][r]);
            float gf = acc1[r] * GSCALE + bf2f((unsigned short)xcur[1][r]);
            float gg = acc2[r] * GSCALE + bf2f((unsigned short)xcur[2][r]);
            float go = acc3[r] * GSCALE + bf2f((unsigned short)xcur[3][r]);
            c[r] = fsig(gf) * c[r] + fsig(gi) * ftanh(gg);
            hv[r] = fsig(go) * ftanh(c[r]);
        }
        {
            int p01 = __builtin_amdgcn_cvt_pk_fp8_f32(hv[0] * HSCALE, hv[1] * HSCALE, 0, false);
            int p23 = __builtin_amdgcn_cvt_pk_fp8_f32(hv[2] * HSCALE, hv[3] * HSCALE, 0, false);
            unsigned char* pg = h_q + (size_t)(t + 1) * 32768 + GOFF + (size_t)chunk * 512
                              + p * 16 + col;
            pg[(rw + 0) * 32] = (unsigned char)(p01 & 0xff);
            pg[(rw + 1) * 32] = (unsigned char)((p01 >> 8) & 0xff);
            pg[(rw + 2) * 32] = (unsigned char)(p23 & 0xff);
            pg[(rw + 3) * 32] = (unsigned char)((p23 >> 8) & 0xff);
        }
        // ---- per-wave drain + publish own flag (no barrier) ----
        asm volatile("s_waitcnt vmcnt(0)" ::: "memory");
        if (lane == 0) {
            plain_pub(&fastf[fid], (unsigned)(t + 2));
            if (mode == 2)
                __hip_atomic_store(&slowf[fid], (unsigned)(t + 2),
                                   __ATOMIC_RELAXED, __HIP_MEMORY_SCOPE_AGENT);
        }
#pragma unroll
        for (int g = 0; g < 4; ++g) xcur[g] = xnxt[g];
    }
}

// ---------------------------------------------------------------------------
// fused tagem + crf. Grid T_SEQ+1 x 512 threads.
// blocks [0..199]: tag GEMM + log_softmax(batch) for page t; em stored with
//   AGENT scope (MALL) and a per-page flag ctrl[512+t] set after drain.
// block 200: crf v2 (register-resident alpha, zero barriers in loop), em
//   read with AGENT loads, gated per 8-page prefetch batch on the flags ->
//   crf overlaps tagem's tail instead of serializing after it.
// ---------------------------------------------------------------------------
__global__ __launch_bounds__(512) void tagem_crf(
    const unsigned char* __restrict__ h_q,
    const unsigned char* __restrict__ linw_q,
    const float* __restrict__ lin_b,
    const int* __restrict__ y,
    const float* __restrict__ start_trans, const float* __restrict__ end_trans,
    const float* __restrict__ trans,
    float* __restrict__ em, unsigned* __restrict__ ctrl,
    float* __restrict__ out)
{
    __shared__ float s_ts[NB * NK];
    __shared__ float s_lse[NK];
    __shared__ float s_trans[NK * NK];
    __shared__ float s_red[NB];
    __shared__ int   s_y[T_SEQ * NB];
    const int blk = blockIdx.x, tid = threadIdx.x;
    unsigned* pflag = ctrl + 512;

    if (blk < T_SEQ) {
        // ================= tagem block =================
        const int t = blk;
        const int w = tid >> 6, lane = tid & 63;
        const int col = lane & 15, quad = lane >> 4;
        if (w < 2) {
            const unsigned char* pa = h_q + (size_t)(t + 1) * 32768 + (size_t)w * 16384
                                    + col * 32 + quad * 8;
            const unsigned char* pw = linw_q + (size_t)col * 1024 + quad * 8;
            f32x4 acc = {0.f, 0.f, 0.f, 0.f};
#pragma unroll 8
            for (int kc = 0; kc < 32; ++kc) {
                u64 a  = *(const u64*)(pa + (size_t)kc * 512);
                u64 bv = *(const u64*)(pw + kc * 32);
                acc = __builtin_amdgcn_mfma_f32_16x16x32_fp8_fp8((long)a, (long)bv, acc, 0, 0, 0);
            }
            if (col < NK) {
                float lb = lin_b[col];
#pragma unroll
                for (int r = 0; r < 4; ++r)
                    s_ts[(w * 16 + quad * 4 + r) * NK + col] = acc[r] * TSCALE + lb;
            }
        }
        __syncthreads();
        if (tid < NK) {
            float m = -1e30f;
            for (int bb = 0; bb < NB; ++bb) m = fmaxf(m, s_ts[bb * NK + tid]);
            float s = 0.f;
            for (int bb = 0; bb < NB; ++bb) s += __expf(s_ts[bb * NK + tid] - m);
            s_lse[tid] = m + __logf(s);
        }
        __syncthreads();
        if (tid < NB * NK) {
            int k = tid - (tid / NK) * NK;
            union { float f; unsigned u; } cv;
            cv.f = s_ts[tid] - s_lse[k];
            __hip_atomic_store((unsigned*)em + (size_t)t * NB * NK + tid, cv.u,
                               __ATOMIC_RELAXED, __HIP_MEMORY_SCOPE_AGENT);
        }
        asm volatile("s_waitcnt vmcnt(0)" ::: "memory");
        __syncthreads();   // all em stores for this page MALL-ack'd
        if (tid == 0) {
            __threadfence();
            __hip_atomic_store(&pflag[t], 1u, __ATOMIC_RELAXED,
                               __HIP_MEMORY_SCOPE_AGENT);
        }
        return;
    }

    // ================= crf block (blk == T_SEQ) =================
    const int gb = tid >> 4;          // batch element 0..31
    const int q  = tid & 15;          // tag lane (active q<9)
    const int lane = tid & 63;
    const int gbase = lane & 48;      // 16-lane group base within wave

    if (tid < NK * NK) s_trans[tid] = trans[tid];
    for (int i = tid; i < T_SEQ * NB; i += 512) s_y[i] = y[i];
    __syncthreads();

    // per-wave page gate (no barriers): lanes 0..7 check 8 flags
    auto wait_pages = [&](int base) {
        for (;;) {
            unsigned v = 1u;
            if (lane < 8 && base + lane < T_SEQ)
                v = __hip_atomic_load(&pflag[base + lane], __ATOMIC_RELAXED,
                                      __HIP_MEMORY_SCOPE_AGENT);
            if (__all((int)(v >= 1u))) break;
            __builtin_amdgcn_s_sleep(2);
        }
    };
    auto emload = [&](int t) -> float {
        union { unsigned u; float f; } cv;
        cv.u = __hip_atomic_load((const unsigned*)em + (size_t)(t * NB + gb) * NK + q,
                                 __ATOMIC_RELAXED, __HIP_MEMORY_SCOPE_AGENT);
        return cv.f;
    };

    float trC[NK];
#pragma unroll
    for (int i = 0; i < NK; ++i)
        trC[i] = (q < NK) ? s_trans[i * NK + q] : 0.f;

    wait_pages(0);
    wait_pages(8);     // pages 0..15 ready (covers t=0 + first prefetch)

    // ---- t = 0 ----
    float emv0 = (q < NK) ? emload(0) : -1e30f;
    int yp = s_y[gb];
    float num = start_trans[yp] + __shfl(emv0, gbase | yp, 64);
    float alpha = (q < NK) ? (start_trans[q] + emv0) : -1e30f;

    // ---- steps t = 1..199, register-pipelined em prefetch (8-deep) ----
    float e[8];
#pragma unroll
    for (int j = 0; j < 8; ++j) {
        int t = 1 + j;
        e[j] = (q < NK && t < T_SEQ) ? emload(t) : -1e30f;
    }
    for (int blk2 = 0; blk2 < 25; ++blk2) {
        float enx[8];
        const int tb = 1 + (blk2 + 1) * 8;
        wait_pages(tb);
#pragma unroll
        for (int j = 0; j < 8; ++j) {
            int t = tb + j;
            enx[j] = (q < NK && t < T_SEQ) ? emload(t) : -1e30f;
        }
#pragma unroll
        for (int j = 0; j < 8; ++j) {
            int t = 1 + blk2 * 8 + j;
            if (t < T_SEQ) {
                float ev = e[j];
                int yc = s_y[t * NB + gb];
                num += s_trans[yp * NK + yc] + __shfl(ev, gbase | yc, 64);
                yp = yc;
                float a_i[NK];
#pragma unroll
                for (int i = 0; i < NK; ++i)
                    a_i[i] = __shfl(alpha, gbase | i, 64) + trC[i];
                float m = a_i[0];
#pragma unroll
                for (int i = 1; i < NK; ++i) m = fmaxf(m, a_i[i]);
                float s = 0.f;
#pragma unroll
                for (int i = 0; i < NK; ++i) s += __expf(a_i[i] - m);
                alpha = (q < NK) ? (ev + m + __logf(s)) : -1e30f;
            }
        }
#pragma unroll
        for (int j = 0; j < 8; ++j) e[j] = enx[j];
    }

    // ---- finish: numerator end + group logsumexp(alpha + end_trans) ----
    num += end_trans[yp];
    float v = (q < NK) ? (alpha + end_trans[q]) : -1e30f;
    float mg = v;
#pragma unroll
    for (int off = 8; off >= 1; off >>= 1)
        mg = fmaxf(mg, __shfl_xor(mg, off, 64));
    float sg = __expf(v - mg);
#pragma unroll
    for (int off = 8; off >= 1; off >>= 1)
        sg += __shfl_xor(sg, off, 64);
    float lz = mg + __logf(sg);
    if (q == 0) s_red[gb] = num - lz;
    __syncthreads();
    if (tid == 0) {
        float tot = 0.f;
        for (int i = 0; i < NB; ++i) tot += s_red[i];
        out[0] = tot;
    }
}

// ---------------------------------------------------------------------------
extern "C" void kernel_launch(void* const* d_in, const int* in_sizes, int n_in,
                              void* d_out, int out_size, void* d_ws, size_t ws_size,
                              hipStream_t stream)
{
    const int*   x           = (const int*)d_in[0];
    const int*   y           = (const int*)d_in[1];
    const float* embed_w     = (const float*)d_in[2];
    const float* W_ih        = (const float*)d_in[3];
    const float* W_hh        = (const float*)d_in[4];
    const float* b_ih        = (const float*)d_in[5];
    const float* b_hh        = (const float*)d_in[6];
    const float* lin_w       = (const float*)d_in[7];
    const float* lin_b       = (const float*)d_in[8];
    const float* start_trans = (const float*)d_in[9];
    const float* end_trans   = (const float*)d_in[10];
    const float* trans       = (const float*)d_in[11];
    float* out = (float*)d_out;

    char* ws = (char*)d_ws;
    unsigned short* xg     = (unsigned short*)(ws);               // 52,428,800 B
    unsigned char*  h_q    = (unsigned char*)(ws + 52428800);     //  6,586,368 B
    unsigned char*  linw_q = (unsigned char*)(ws + 59015168);     //     16,384 B
    float*          em     = (float*)(ws + 65601536);             //    230,400 B
    unsigned*       ctrl   = (unsigned*)(ws + 65831936);          //      8,192 B
    float*          biasg  = (float*)(ws + 65840128);             //     16,384 B
    unsigned short* emb_bf = (unsigned short*)(ws + 65856512);    //  4,096,000 B
    unsigned short* wih_bf = (unsigned short*)(ws + 69952512);    //  2,621,440 B

    prep_all<<<dim3(T_SEQ + 64), 256, 0, stream>>>(x, embed_w, W_ih, b_ih, b_hh,
                                                   lin_w, emb_bf, wih_bf, biasg,
                                                   linw_q, ctrl);

    lstm_kernel<<<dim3(256), 256, 0, stream>>>(W_hh, emb_bf, wih_bf, biasg,
                                               xg, h_q, ctrl);

    tagem_crf<<<dim3(T_SEQ + 1), 512, 0, stream>>>(h_q, linw_q, lin_b, y,
                                                   start_trans, end_trans, trans,
                                                   em, ctrl, out);
}

// Round 9
// 946.136 us; speedup vs baseline: 1.1614x; 1.1614x over previous
//
#include <hip/hip_runtime.h>

#define T_SEQ 200
#define NB    32
#define NE    300
#define NH    1000
#define NK    9
#define NJ    4096          // xg rows per t
#define EPD   320           // padded embed K
#define WSCALE 256.0f
#define HSCALE 16.0f
#define LSCALE 512.0f
#define GSCALE (1.0f / (256.0f * 16.0f))
#define TSCALE (1.0f / (16.0f * 512.0f))

typedef __attribute__((ext_vector_type(4))) float f32x4;
typedef __attribute__((ext_vector_type(8))) short s16x8;
typedef __attribute__((ext_vector_type(4))) short s16x4;
typedef unsigned long long u64;

__device__ __forceinline__ unsigned short f2bf(float f) {
    union { float f; unsigned u; } v; v.f = f;
    unsigned r = v.u + 0x7FFFu + ((v.u >> 16) & 1u);   // RNE
    return (unsigned short)(r >> 16);
}
__device__ __forceinline__ float bf2f(unsigned short h) {
    union { unsigned u; float f; } v; v.u = ((unsigned)h) << 16;
    return v.f;
}
__device__ __forceinline__ float ftanh(float x) {
    float e = __expf(fminf(2.f * x, 80.f));
    return (e - 1.f) / (e + 1.f);
}
__device__ __forceinline__ float fsig(float x) {
    return 1.f / (1.f + __expf(-x));
}
// non-temporal dword load: no L1 allocate -> served by (XCD) L2
__device__ __forceinline__ unsigned nt_poll(const unsigned* p) {
    unsigned r;
    asm volatile("global_load_dword %0, %1, off nt\n\t"
                 "s_waitcnt vmcnt(0)"
                 : "=v"(r) : "v"(p) : "memory");
    return r;
}
// plain store, compiler-opaque (workgroup-scope relaxed -> global_store_dword)
__device__ __forceinline__ void plain_pub(unsigned* p, unsigned v) {
    __hip_atomic_store(p, v, __ATOMIC_RELAXED, __HIP_MEMORY_SCOPE_WORKGROUP);
}

// ---------------------------------------------------------------------------
// ctrl map (dwords):
// [0..63]    slowf group0 (agent/MALL, 64 per-wave flags)
// [64..127]  slowf group1
// [128..191] fastf group0 (plain/L2, 64 per-wave flags)
// [192..255] fastf group1
// [256..455] done[t]
// [480..495] XCD tickets | [496] arrivals | [497] winners (w0|w1<<8, init -1)
// [498] prod ticket | [499] mode verdict (0=undecided, 1=nt/L2, 2=agent/MALL)
// [512..711] em page flags (tagem_crf)
// ---------------------------------------------------------------------------
// fused prep: blocks [0..199] = embedding gather+cvt (+ctrl init at blk 0),
// blocks [200..263] = W_ih cvt + bias + lin_w fp8 quant.
// ---------------------------------------------------------------------------
__global__ __launch_bounds__(256) void prep_all(
    const int* __restrict__ x, const float* __restrict__ embed_w,
    const float* __restrict__ W_ih, const float* __restrict__ b_ih,
    const float* __restrict__ b_hh, const float* __restrict__ lin_w,
    unsigned short* __restrict__ emb_bf, unsigned short* __restrict__ wih_bf,
    float* __restrict__ biasg, unsigned char* __restrict__ linw_q,
    unsigned* __restrict__ ctrl)
{
    const int blk = blockIdx.x, tid = threadIdx.x;
    if (blk < T_SEQ) {
        const int t = blk;
        if (blk == 0) {
            for (int i = tid; i < 2048; i += 256)
                ctrl[i] = (i == 497) ? 0xffffffffu : 0u;
        }
        for (int idx = tid; idx < NB * EPD; idx += 256) {
            int b = idx / EPD, e = idx - b * EPD;
            float v = (e < NE) ? embed_w[(size_t)x[t * NB + b] * NE + e] : 0.f;
            emb_bf[((size_t)t * NB + b) * EPD + e] = f2bf(v);
        }
        return;
    }
    const int b2 = blk - T_SEQ;      // 0..63
    for (int idx = tid; idx < 64 * EPD; idx += 256) {
        int jr = idx / EPD, e = idx - jr * EPD;
        int jp = b2 * 64 + jr;
        int wgu = jp >> 7, rr = jp & 127, g = rr >> 5, uu = rr & 31;
        int m = wgu * 32 + uu;
        float v = (m < NH && e < NE) ? W_ih[(size_t)(g * NH + m) * NE + e] : 0.f;
        wih_bf[(size_t)jp * EPD + e] = f2bf(v);
    }
    if (tid < 64) {
        int jp = b2 * 64 + tid;
        int wgu = jp >> 7, rr = jp & 127, g = rr >> 5, uu = rr & 31;
        int m = wgu * 32 + uu;
        biasg[jp] = (m < NH) ? (b_ih[g * NH + m] + b_hh[g * NH + m]) : 0.f;
    }
    if (b2 < 16) {
        int n = b2, k = tid * 4;
        float v0 = (n < NK && k + 0 < NH) ? lin_w[(size_t)n * NH + k + 0] * LSCALE : 0.f;
        float v1 = (n < NK && k + 1 < NH) ? lin_w[(size_t)n * NH + k + 1] * LSCALE : 0.f;
        float v2 = (n < NK && k + 2 < NH) ? lin_w[(size_t)n * NH + k + 2] * LSCALE : 0.f;
        float v3 = (n < NK && k + 3 < NH) ? lin_w[(size_t)n * NH + k + 3] * LSCALE : 0.f;
        int p01 = __builtin_amdgcn_cvt_pk_fp8_f32(v0, v1, 0, false);
        int p23 = __builtin_amdgcn_cvt_pk_fp8_f32(v2, v3, 0, false);
        ((unsigned*)linw_q)[n * 256 + tid] =
            ((unsigned)p01 & 0xffffu) | ((unsigned)p23 << 16);
    }
}

// ---------------------------------------------------------------------------
__device__ __forceinline__ int gate_xg(unsigned* done, int ready, int tn, int lane) {
    while (ready <= tn) {
        unsigned v = 64u;
        if (lane < 8 && ready + lane < T_SEQ)
            v = __hip_atomic_load(&done[ready + lane], __ATOMIC_RELAXED,
                                  __HIP_MEMORY_SCOPE_AGENT);
        unsigned m = (unsigned)__ballot((int)(v >= 64u)) & 255u;
        if (m & 1u) {
            unsigned run = (m == 255u) ? 8u : (unsigned)__builtin_ctz(~m);
            ready += (int)run;
        } else {
            __builtin_amdgcn_s_sleep(1);
        }
    }
    return ready;
}

// ---------------------------------------------------------------------------
// mega kernel (FROZEN R3/R4 structure — best measured: ~770-804 µs; five
// structural variants of this loop each regressed 0.5-2.5 µs/step).
// grid 256, 1 WG/CU. TWO winner XCDs each host an independent 32-WG consumer
// group handling 16 batch lanes. Per consumer WG: 2 compute waves (p=0,1),
// each owning its OWN readiness flag (64 flags/group) -> NO barriers in the
// recurrence loop; waves 2,3 exit before the loop. The xg gate (producer
// done[t+2]) is merged into the h-flag poll with 2-step lookahead. xg(t+1)
// prefetch issued right after the a-burst (full MFMA phase to retire).
// Publish after plain vmcnt(0). Remaining 192 WGs = producers, then exit.
// Flag transport self-tested at startup (ctrl[499]).
// ---------------------------------------------------------------------------
__global__ __launch_bounds__(256, 1) void lstm_kernel(
    const float* __restrict__ W_hh,
    const unsigned short* __restrict__ emb_bf,
    const unsigned short* __restrict__ wih_bf,
    const float* __restrict__ biasg,
    unsigned short* __restrict__ xg,
    unsigned char* __restrict__ h_q,
    unsigned* __restrict__ ctrl)
{
    __shared__ __align__(16) unsigned char s_w[128 * 1024];   // 131,072 B
    __shared__ int s_chunk, s_grp, s_pid, s_mode;

    const int tid = threadIdx.x;

    // ---- election (startup only, MALL atomics) ----
    if (tid == 0) {
        unsigned xcc;
        asm volatile("s_getreg_b32 %0, hwreg(HW_REG_XCC_ID)" : "=s"(xcc));
        xcc &= 15u;
        unsigned myidx = __hip_atomic_fetch_add(&ctrl[480 + xcc], 1u,
                             __ATOMIC_RELAXED, __HIP_MEMORY_SCOPE_AGENT);
        __threadfence();
        unsigned tot = __hip_atomic_fetch_add(&ctrl[496], 1u,
                             __ATOMIC_RELAXED, __HIP_MEMORY_SCOPE_AGENT);
        if (tot == 255u) {
            __threadfence();
            unsigned w0 = 0xffu, w1 = 0xffu;
            for (unsigned xx = 0; xx < 16; ++xx) {
                unsigned cx = __hip_atomic_load(&ctrl[480 + xx], __ATOMIC_RELAXED,
                                                __HIP_MEMORY_SCOPE_AGENT);
                if (cx >= 32u) {
                    if (w0 == 0xffu) w0 = xx;
                    else { w1 = xx; break; }
                }
            }
            __hip_atomic_store(&ctrl[497], w0 | (w1 << 8), __ATOMIC_RELAXED,
                               __HIP_MEMORY_SCOPE_AGENT);
        }
        unsigned win;
        do {
            win = __hip_atomic_load(&ctrl[497], __ATOMIC_RELAXED,
                                    __HIP_MEMORY_SCOPE_AGENT);
        } while (win == 0xffffffffu);
        unsigned w0 = win & 0xffu, w1 = (win >> 8) & 0xffu;
        int grp = -1;
        if (xcc == w0 && myidx < 32u) grp = 0;
        else if (xcc == w1 && myidx < 32u) grp = 1;
        s_grp = grp;
        s_chunk = (grp >= 0) ? (int)myidx : -1;
        s_pid = (grp >= 0) ? -1
                     : (int)__hip_atomic_fetch_add(&ctrl[498], 1u,
                           __ATOMIC_RELAXED, __HIP_MEMORY_SCOPE_AGENT);
    }
    __syncthreads();
    const int chunk = s_chunk;
    const int w = tid >> 6, lane = tid & 63;
    const int col = lane & 15, quad = lane >> 4;
    unsigned* done = ctrl + 256;

    if (chunk < 0) {
        // =================== PRODUCER: xg projection tiles ===================
        const int pid = s_pid;
        for (int g = pid; g < T_SEQ * 64; g += 192) {
            const int t = g >> 6, jt = g & 63;
            const unsigned short* eb = emb_bf + (size_t)t * NB * EPD;
            const unsigned short* wb = wih_bf + (size_t)(jt * 64 + w * 16 + col) * EPD;
            const unsigned short* ea0 = eb + (size_t)col * EPD;
            const unsigned short* ea1 = eb + (size_t)(16 + col) * EPD;

            f32x4 acc0 = {0.f, 0.f, 0.f, 0.f};
            f32x4 acc1 = {0.f, 0.f, 0.f, 0.f};
#pragma unroll
            for (int kc = 0; kc < EPD / 32; ++kc) {
                int ko = kc * 32 + quad * 8;
                s16x8 a0 = *(const s16x8*)&ea0[ko];
                s16x8 a1 = *(const s16x8*)&ea1[ko];
                s16x8 bb = *(const s16x8*)&wb[ko];
                acc0 = __builtin_amdgcn_mfma_f32_16x16x32_bf16(a0, bb, acc0, 0, 0, 0);
                acc1 = __builtin_amdgcn_mfma_f32_16x16x32_bf16(a1, bb, acc1, 0, 0, 0);
            }
            const int jp = jt * 64 + w * 16 + col;
            const float bi = biasg[jp];
            size_t base = ((size_t)t * NJ + jp) * NB;
            union { s16x4 v; u64 q; } p0, p1;
#pragma unroll
            for (int r = 0; r < 4; ++r) {
                p0.v[r] = (short)f2bf(acc0[r] + bi);
                p1.v[r] = (short)f2bf(acc1[r] + bi);
            }
            __hip_atomic_store((u64*)&xg[base + quad * 4], p0.q,
                               __ATOMIC_RELAXED, __HIP_MEMORY_SCOPE_AGENT);
            __hip_atomic_store((u64*)&xg[base + 16 + quad * 4], p1.q,
                               __ATOMIC_RELAXED, __HIP_MEMORY_SCOPE_AGENT);
            __syncthreads();   // stores vmcnt-drained (MALL-ack'd)
            if (tid == 0)
                __hip_atomic_fetch_add(&done[t], 1u, __ATOMIC_RELAXED,
                                       __HIP_MEMORY_SCOPE_AGENT);
        }
        return;
    }

    // ===================== CONSUMER: LSTM recurrence =====================
    const int grp = s_grp;
    const size_t GOFF = (size_t)grp * 16384;     // group's half of each 32 KB page
    unsigned* slowf = ctrl + grp * 64;           // agent fallback flags (64)
    unsigned* fastf = ctrl + 128 + grp * 64;     // plain/L2 flags (64)
    unsigned* s_w32 = (unsigned*)s_w;

    // ---- stage W_hh -> LDS fp8 x256, XOR-swizzled on 8-B blocks ----
    for (int idx = tid; idx < 128 * 256; idx += 256) {
        int r = idx >> 8, dw = idx & 255;
        int g = r >> 5, uu = r & 31, m = chunk * 32 + uu;
        float4 w4 = make_float4(0.f, 0.f, 0.f, 0.f);
        if (m < NH && dw < 250)
            w4 = *(const float4*)&W_hh[(size_t)(g * NH + m) * NH + dw * 4];
        int p0 = __builtin_amdgcn_cvt_pk_fp8_f32(w4.x * WSCALE, w4.y * WSCALE, 0, false);
        int p1 = __builtin_amdgcn_cvt_pk_fp8_f32(w4.z * WSCALE, w4.w * WSCALE, 0, false);
        unsigned v = ((unsigned)p0 & 0xffffu) | ((unsigned)p1 << 16);
        int kb = dw >> 1;
        int kbs = kb ^ (r & 15);
        s_w32[r * 256 + (kbs << 1) + (dw & 1)] = v;
    }
    // ---- zero own 512-B chunk of page 0 (plain store -> local L2) ----
    if (tid < 128)
        *(unsigned*)(h_q + GOFF + (size_t)chunk * 512 + tid * 4) = 0u;
    __syncthreads();   // W tile in LDS; page-0 zeros vmcnt-drained (all waves)
    if (tid == 0) {
        plain_pub(&fastf[chunk * 2 + 0], 1u);
        plain_pub(&fastf[chunk * 2 + 1], 1u);
        __hip_atomic_store(&slowf[chunk * 2 + 0], 1u, __ATOMIC_RELAXED,
                           __HIP_MEMORY_SCOPE_AGENT);
        __hip_atomic_store(&slowf[chunk * 2 + 1], 1u, __ATOMIC_RELAXED,
                           __HIP_MEMORY_SCOPE_AGENT);
    }
    // ---- nt-visibility self-test; group0/chunk0 decides, ctrl[499] bcast ----
    if (grp == 0 && chunk == 0 && w == 0) {
        int md = 2;
        for (int it = 0; it < 8192; ++it) {
            unsigned v = nt_poll(&fastf[lane]);
            if (__all((int)(v >= 1u))) { md = 1; break; }
        }
        if (lane == 0) {
            __hip_atomic_store(&ctrl[499], (unsigned)md, __ATOMIC_RELAXED,
                               __HIP_MEMORY_SCOPE_AGENT);
            s_mode = md;
        }
    } else if (tid == 0) {
        unsigned m;
        do {
            m = __hip_atomic_load(&ctrl[499], __ATOMIC_RELAXED,
                                  __HIP_MEMORY_SCOPE_AGENT);
        } while (m == 0u);
        s_mode = (int)m;
    }
    __syncthreads();
    const int mode = s_mode;

    // ---- waves 2,3 exit: no barriers remain in the recurrence loop ----
    if (w >= 2) return;
    const int p = w;                 // p-half of the chunk's 32 units
    const int fid = chunk * 2 + w;   // this wave's own flag

    // ---- gated xg load t=0; pre-gate page 1 for issue at top of t=0 ----
    int ready = gate_xg(done, 0, 1, lane);
    s16x4 xcur[4], xnxt[4];
#pragma unroll
    for (int g = 0; g < 4; ++g)
        xcur[g] = *(const s16x4*)&xg[((size_t)0 * NJ + chunk * 128 + (2 * g + p) * 16 + col) * NB
                                     + grp * 16 + quad * 4];

    float c[4] = {0.f, 0.f, 0.f, 0.f};
    const int rw = quad * 4;
    const int boff = col * 32 + quad * 8;

    for (int t = 0; t < T_SEQ; ++t) {
        // ---- merged poll: h flags for page t + producer gate for page t+2 ----
        const unsigned need = (unsigned)(t + 1);
        const int gt = t + 2;
        bool gate_pending = (gt < T_SEQ) && (ready <= gt);
        if (mode == 1) {
            for (;;) {
                unsigned v = nt_poll(&fastf[lane]);
                bool hok = __all((int)(v >= need));
                if (gate_pending) {
                    unsigned d = 64u;
                    if (lane < 8 && ready + lane < T_SEQ)
                        d = __hip_atomic_load(&done[ready + lane], __ATOMIC_RELAXED,
                                              __HIP_MEMORY_SCOPE_AGENT);
                    unsigned m = (unsigned)__ballot((int)(d >= 64u)) & 255u;
                    if (m & 1u)
                        ready += (m == 255u) ? 8 : (int)__builtin_ctz(~m);
                    gate_pending = (ready <= gt);
                }
                if (hok && !gate_pending) break;
            }
        } else {
            for (;;) {
                unsigned v = __hip_atomic_load(&slowf[lane], __ATOMIC_RELAXED,
                                               __HIP_MEMORY_SCOPE_AGENT);
                bool hok = __all((int)(v >= need));
                if (gate_pending) {
                    unsigned d = 64u;
                    if (lane < 8 && ready + lane < T_SEQ)
                        d = __hip_atomic_load(&done[ready + lane], __ATOMIC_RELAXED,
                                              __HIP_MEMORY_SCOPE_AGENT);
                    unsigned m = (unsigned)__ballot((int)(d >= 64u)) & 255u;
                    if (m & 1u)
                        ready += (m == 255u) ? 8 : (int)__builtin_ctz(~m);
                    gate_pending = (ready <= gt);
                }
                if (hok && !gate_pending) break;
            }
        }
        asm volatile("" ::: "memory");

        // ---- burst load group-local page t (16 KB, local L2) ----
        const unsigned char* pb = h_q + (size_t)t * 32768 + GOFF + boff;
        u64 a[32];
#pragma unroll
        for (int kc = 0; kc < 32; ++kc)
            a[kc] = *(const u64*)(pb + (size_t)kc * 512);

        // ---- xg prefetch t+1 (already gated; MALL latency rides under MFMA,
        //      issued AFTER the a-burst so a[] is waitable at vmcnt(4)) ----
        if (t + 1 < T_SEQ) {
#pragma unroll
            for (int g = 0; g < 4; ++g)
                xnxt[g] = *(const s16x4*)&xg[((size_t)(t + 1) * NJ + chunk * 128 + (2 * g + p) * 16 + col) * NB
                                             + grp * 16 + quad * 4];
        }

        f32x4 acc0 = {0.f, 0.f, 0.f, 0.f};
        f32x4 acc1 = {0.f, 0.f, 0.f, 0.f};
        f32x4 acc2 = {0.f, 0.f, 0.f, 0.f};
        f32x4 acc3 = {0.f, 0.f, 0.f, 0.f};
#pragma unroll
        for (int kc = 0; kc < 32; ++kc) {
            int kb = kc * 4 + quad;
            u64 b0 = *(const u64*)&s_w[((0 * 2 + p) * 16 + col) * 1024 + ((kb ^ col) << 3)];
            u64 b1 = *(const u64*)&s_w[((1 * 2 + p) * 16 + col) * 1024 + ((kb ^ col) << 3)];
            u64 b2 = *(const u64*)&s_w[((2 * 2 + p) * 16 + col) * 1024 + ((kb ^ col) << 3)];
            u64 b3 = *(const u64*)&s_w[((3 * 2 + p) * 16 + col) * 1024 + ((kb ^ col) << 3)];
            acc0 = __builtin_amdgcn_mfma_f32_16x16x32_fp8_fp8((long)a[kc], (long)b0, acc0, 0, 0, 0);
            acc1 = __builtin_amdgcn_mfma_f32_16x16x32_fp8_fp8((long)a[kc], (long)b1, acc1, 0, 0, 0);
            acc2 = __builtin_amdgcn_mfma_f32_16x16x32_fp8_fp8((long)a[kc], (long)b2, acc2, 0, 0, 0);
            acc3 = __builtin_amdgcn_mfma_f32_16x16x32_fp8_fp8((long)a[kc], (long)b3, acc3, 0, 0, 0);
        }

        // ---- epilogue: 4 cells; direct byte stores (group-local layout) ----
        float hv[4];
#pragma unroll
        for (int r = 0; r < 4; ++r) {
            float gi = acc0[r] * GSCALE + bf2f((unsigned short)xcur[0][r]);
            float gf = acc1[r] * GSCALE + bf2f((unsigned short)xcur[1][r]);
            float gg = acc2[r] * GSCALE + bf2f((unsigned short)xcur[2][r]);
            float go = acc3[r] * GSCALE + bf2f((unsigned short)xcur[3][r]);
            c[r] = fsig(gf) * c[r] + fsig(gi) * ftanh(gg);
            hv[r] = fsig(go) * ftanh(c[r]);
        }
        {
            int p01 = __builtin_amdgcn_cvt_pk_fp8_f32(hv[0] * HSCALE, hv[1] * HSCALE, 0, false);
            int p23 = __builtin_amdgcn_cvt_pk_fp8_f32(hv[2] * HSCALE, hv[3] * HSCALE, 0, false);
            unsigned char* pg = h_q + (size_t)(t + 1) * 32768 + GOFF + (size_t)chunk * 512
                              + p * 16 + col;
            pg[(rw + 0) * 32] = (unsigned char)(p01 & 0xff);
            pg[(rw + 1) * 32] = (unsigned char)((p01 >> 8) & 0xff);
            pg[(rw + 2) * 32] = (unsigned char)(p23 & 0xff);
            pg[(rw + 3) * 32] = (unsigned char)((p23 >> 8) & 0xff);
        }
        // ---- per-wave drain + publish own flag (no barrier) ----
        asm volatile("s_waitcnt vmcnt(0)" ::: "memory");
        if (lane == 0) {
            plain_pub(&fastf[fid], (unsigned)(t + 2));
            if (mode == 2)
                __hip_atomic_store(&slowf[fid], (unsigned)(t + 2),
                                   __ATOMIC_RELAXED, __HIP_MEMORY_SCOPE_AGENT);
        }
#pragma unroll
        for (int g = 0; g < 4; ++g) xcur[g] = xnxt[g];
    }
}

// ---------------------------------------------------------------------------
// fused tagem + crf. Grid T_SEQ+1 x 512 threads.
// blocks [0..199]: tag GEMM + log_softmax(batch) for page t; em stored with
//   AGENT scope (MALL) and a per-page flag ctrl[512+t] set after drain.
// block 200: crf v2 (register-resident alpha, zero barriers in loop), em
//   read with AGENT loads, gated per 8-page prefetch batch on the flags ->
//   crf overlaps tagem's tail instead of serializing after it.
// ---------------------------------------------------------------------------
__global__ __launch_bounds__(512) void tagem_crf(
    const unsigned char* __restrict__ h_q,
    const unsigned char* __restrict__ linw_q,
    const float* __restrict__ lin_b,
    const int* __restrict__ y,
    const float* __restrict__ start_trans, const float* __restrict__ end_trans,
    const float* __restrict__ trans,
    float* __restrict__ em, unsigned* __restrict__ ctrl,
    float* __restrict__ out)
{
    __shared__ float s_ts[NB * NK];
    __shared__ float s_lse[NK];
    __shared__ float s_trans[NK * NK];
    __shared__ float s_red[NB];
    __shared__ int   s_y[T_SEQ * NB];
    const int blk = blockIdx.x, tid = threadIdx.x;
    unsigned* pflag = ctrl + 512;

    if (blk < T_SEQ) {
        // ================= tagem block =================
        const int t = blk;
        const int w = tid >> 6, lane = tid & 63;
        const int col = lane & 15, quad = lane >> 4;
        if (w < 2) {
            const unsigned char* pa = h_q + (size_t)(t + 1) * 32768 + (size_t)w * 16384
                                    + col * 32 + quad * 8;
            const unsigned char* pw = linw_q + (size_t)col * 1024 + quad * 8;
            f32x4 acc = {0.f, 0.f, 0.f, 0.f};
#pragma unroll 8
            for (int kc = 0; kc < 32; ++kc) {
                u64 a  = *(const u64*)(pa + (size_t)kc * 512);
                u64 bv = *(const u64*)(pw + kc * 32);
                acc = __builtin_amdgcn_mfma_f32_16x16x32_fp8_fp8((long)a, (long)bv, acc, 0, 0, 0);
            }
            if (col < NK) {
                float lb = lin_b[col];
#pragma unroll
                for (int r = 0; r < 4; ++r)
                    s_ts[(w * 16 + quad * 4 + r) * NK + col] = acc[r] * TSCALE + lb;
            }
        }
        __syncthreads();
        if (tid < NK) {
            float m = -1e30f;
            for (int bb = 0; bb < NB; ++bb) m = fmaxf(m, s_ts[bb * NK + tid]);
            float s = 0.f;
            for (int bb = 0; bb < NB; ++bb) s += __expf(s_ts[bb * NK + tid] - m);
            s_lse[tid] = m + __logf(s);
        }
        __syncthreads();
        if (tid < NB * NK) {
            int k = tid - (tid / NK) * NK;
            union { float f; unsigned u; } cv;
            cv.f = s_ts[tid] - s_lse[k];
            __hip_atomic_store((unsigned*)em + (size_t)t * NB * NK + tid, cv.u,
                               __ATOMIC_RELAXED, __HIP_MEMORY_SCOPE_AGENT);
        }
        asm volatile("s_waitcnt vmcnt(0)" ::: "memory");
        __syncthreads();   // all em stores for this page MALL-ack'd
        if (tid == 0) {
            __threadfence();
            __hip_atomic_store(&pflag[t], 1u, __ATOMIC_RELAXED,
                               __HIP_MEMORY_SCOPE_AGENT);
        }
        return;
    }

    // ================= crf block (blk == T_SEQ) =================
    const int gb = tid >> 4;          // batch element 0..31
    const int q  = tid & 15;          // tag lane (active q<9)
    const int lane = tid & 63;
    const int gbase = lane & 48;      // 16-lane group base within wave

    if (tid < NK * NK) s_trans[tid] = trans[tid];
    for (int i = tid; i < T_SEQ * NB; i += 512) s_y[i] = y[i];
    __syncthreads();

    // per-wave page gate (no barriers): lanes 0..7 check 8 flags
    auto wait_pages = [&](int base) {
        for (;;) {
            unsigned v = 1u;
            if (lane < 8 && base + lane < T_SEQ)
                v = __hip_atomic_load(&pflag[base + lane], __ATOMIC_RELAXED,
                                      __HIP_MEMORY_SCOPE_AGENT);
            if (__all((int)(v >= 1u))) break;
            __builtin_amdgcn_s_sleep(2);
        }
    };
    auto emload = [&](int t) -> float {
        union { unsigned u; float f; } cv;
        cv.u = __hip_atomic_load((const unsigned*)em + (size_t)(t * NB + gb) * NK + q,
                                 __ATOMIC_RELAXED, __HIP_MEMORY_SCOPE_AGENT);
        return cv.f;
    };

    float trC[NK];
#pragma unroll
    for (int i = 0; i < NK; ++i)
        trC[i] = (q < NK) ? s_trans[i * NK + q] : 0.f;

    wait_pages(0);
    wait_pages(8);     // pages 0..15 ready (covers t=0 + first prefetch)

    // ---- t = 0 ----
    float emv0 = (q < NK) ? emload(0) : -1e30f;
    int yp = s_y[gb];
    float num = start_trans[yp] + __shfl(emv0, gbase | yp, 64);
    float alpha = (q < NK) ? (start_trans[q] + emv0) : -1e30f;

    // ---- steps t = 1..199, register-pipelined em prefetch (8-deep) ----
    float e[8];
#pragma unroll
    for (int j = 0; j < 8; ++j) {
        int t = 1 + j;
        e[j] = (q < NK && t < T_SEQ) ? emload(t) : -1e30f;
    }
    for (int blk2 = 0; blk2 < 25; ++blk2) {
        float enx[8];
        const int tb = 1 + (blk2 + 1) * 8;
        wait_pages(tb);
#pragma unroll
        for (int j = 0; j < 8; ++j) {
            int t = tb + j;
            enx[j] = (q < NK && t < T_SEQ) ? emload(t) : -1e30f;
        }
#pragma unroll
        for (int j = 0; j < 8; ++j) {
            int t = 1 + blk2 * 8 + j;
            if (t < T_SEQ) {
                float ev = e[j];
                int yc = s_y[t * NB + gb];
                num += s_trans[yp * NK + yc] + __shfl(ev, gbase | yc, 64);
                yp = yc;
                float a_i[NK];
#pragma unroll
                for (int i = 0; i < NK; ++i)
                    a_i[i] = __shfl(alpha, gbase | i, 64) + trC[i];
                float m = a_i[0];
#pragma unroll
                for (int i = 1; i < NK; ++i) m = fmaxf(m, a_i[i]);
                float s = 0.f;
#pragma unroll
                for (int i = 0; i < NK; ++i) s += __expf(a_i[i] - m);
                alpha = (q < NK) ? (ev + m + __logf(s)) : -1e30f;
            }
        }
#pragma unroll
        for (int j = 0; j < 8; ++j) e[j] = enx[j];
    }

    // ---- finish: numerator end + group logsumexp(alpha + end_trans) ----
    num += end_trans[yp];
    float v = (q < NK) ? (alpha + end_trans[q]) : -1e30f;
    float mg = v;
#pragma unroll
    for (int off = 8; off >= 1; off >>= 1)
        mg = fmaxf(mg, __shfl_xor(mg, off, 64));
    float sg = __expf(v - mg);
#pragma unroll
    for (int off = 8; off >= 1; off >>= 1)
        sg += __shfl_xor(sg, off, 64);
    float lz = mg + __logf(sg);
    if (q == 0) s_red[gb] = num - lz;
    __syncthreads();
    if (tid == 0) {
        float tot = 0.f;
        for (int i = 0; i < NB; ++i) tot += s_red[i];
        out[0] = tot;
    }
}

// ---------------------------------------------------------------------------
extern "C" void kernel_launch(void* const* d_in, const int* in_sizes, int n_in,
                              void* d_out, int out_size, void* d_ws, size_t ws_size,
                              hipStream_t stream)
{
    const int*   x           = (const int*)d_in[0];
    const int*   y           = (const int*)d_in[1];
    const float* embed_w     = (const float*)d_in[2];
    const float* W_ih        = (const float*)d_in[3];
    const float* W_hh        = (const float*)d_in[4];
    const float* b_ih        = (const float*)d_in[5];
    const float* b_hh        = (const float*)d_in[6];
    const float* lin_w       = (const float*)d_in[7];
    const float* lin_b       = (const float*)d_in[8];
    const float* start_trans = (const float*)d_in[9];
    const float* end_trans   = (const float*)d_in[10];
    const float* trans       = (const float*)d_in[11];
    float* out = (float*)d_out;

    char* ws = (char*)d_ws;
    unsigned short* xg     = (unsigned short*)(ws);               // 52,428,800 B
    unsigned char*  h_q    = (unsigned char*)(ws + 52428800);     //  6,586,368 B
    unsigned char*  linw_q = (unsigned char*)(ws + 59015168);     //     16,384 B
    float*          em     = (float*)(ws + 65601536);             //    230,400 B
    unsigned*       ctrl   = (unsigned*)(ws + 65831936);          //      8,192 B
    float*          biasg  = (float*)(ws + 65840128);             //     16,384 B
    unsigned short* emb_bf = (unsigned short*)(ws + 65856512);    //  4,096,000 B
    unsigned short* wih_bf = (unsigned short*)(ws + 69952512);    //  2,621,440 B

    prep_all<<<dim3(T_SEQ + 64), 256, 0, stream>>>(x, embed_w, W_ih, b_ih, b_hh,
                                                   lin_w, emb_bf, wih_bf, biasg,
                                                   linw_q, ctrl);

    lstm_kernel<<<dim3(256), 256, 0, stream>>>(W_hh, emb_bf, wih_bf, biasg,
                                               xg, h_q, ctrl);

    tagem_crf<<<dim3(T_SEQ + 1), 512, 0, stream>>>(h_q, linw_q, lin_b, y,
                                                   start_trans, end_trans, trans,
                                                   em, ctrl, out);
}